// Round 1
// baseline (774.680 us; speedup 1.0000x reference)
//
#include <hip/hip_runtime.h>
#include <cstdint>
#include <cstddef>

#define NLAB 128
#define TT   512
#define BB   512
#define PAD_ 0
#define BOS_ 1
#define EOS_ 2

// ---- mask dtype hedge: bool(1B) vs int32(4B) -------------------------------
// mask[0][1] is always true (lengths >= T/2 = 256). If stored as int32, the
// byte at offset 1 is the high byte of element 0 => 0. If bool, it's 1.
__device__ __forceinline__ bool mask_is_i32(const unsigned char* m8) {
    return m8[1] == 0;
}
__device__ __forceinline__ bool mask_at(const unsigned char* m8, int idx, bool isi) {
    if (isi) return ((const int*)m8)[idx] != 0;
    return m8[idx] != 0;
}

// ---- E = exp(transitions) --------------------------------------------------
__global__ void crf_exp_tr(const float* __restrict__ tr, float* __restrict__ E) {
    int idx = blockIdx.x * blockDim.x + threadIdx.x;
    if (idx < NLAB * NLAB) E[idx] = __expf(tr[idx]);  // exp(-10000) -> 0 exactly
}

// ---- gold path score: one wave (64 threads) per batch ----------------------
__global__ void crf_gold(const float* __restrict__ feats,
                         const int*   __restrict__ tags,
                         const unsigned char* __restrict__ m8,
                         const float* __restrict__ tr,
                         float* __restrict__ gold_out) {
    const int b = blockIdx.x;
    const int l = threadIdx.x;  // 0..63
    const bool isi = mask_is_i32(m8);

    float part = 0.0f;
    int   cnt  = 0;
    for (int t = l; t < TT; t += 64) {
        const int idx = b * TT + t;
        const bool m = mask_at(m8, idx, isi);
        cnt += m ? 1 : 0;
        const int tag = tags[idx];
        if (t == 0) {
            // emis[b,0] + tr[BOS, tag0]  (unconditional in the reference)
            part += feats[(size_t)idx * NLAB + tag] + tr[BOS_ * NLAB + tag];
        } else if (m) {
            const int tprev = tags[idx - 1];
            part += feats[(size_t)idx * NLAB + tag] + tr[tprev * NLAB + tag];
        }
    }
    #pragma unroll
    for (int off = 32; off > 0; off >>= 1) {
        part += __shfl_down(part, off, 64);
        cnt  += __shfl_down(cnt,  off, 64);
    }
    if (l == 0) {
        const int vlen = cnt - 1;
        const int last = tags[b * TT + vlen];
        gold_out[b] = part + tr[last * NLAB + EOS_];
    }
}

// ---- forward algorithm: one block (128 thr) per batch ----------------------
// Thread j owns fv[j] and E[:,j] resident in 128 VGPRs. Per step:
//   m = blockmax(fv); p[j] = exp(fv[j]-m) -> LDS; s_j = sum_k p[k]*Ecol[k];
//   fv[j] = m + log(s_j) + feat[t][j]
__global__ __launch_bounds__(NLAB) void crf_forward(
        const float* __restrict__ feats,
        const unsigned char* __restrict__ m8,
        const float* __restrict__ tr,
        const float* __restrict__ E,
        float* __restrict__ logZ_out) {
    const int b = blockIdx.x;
    const int j = threadIdx.x;
    const bool isi = mask_is_i32(m8);

    __shared__ __align__(16) float p_sh[NLAB];
    __shared__ float red[2];
    __shared__ float red2[2];
    __shared__ int   len_sh;

    // sequence length = popcount of mask row (mask is a monotone prefix)
    int cnt = 0;
    #pragma unroll
    for (int t = j; t < TT; t += NLAB)
        cnt += mask_at(m8, b * TT + t, isi) ? 1 : 0;
    if (j == 0) len_sh = 0;
    __syncthreads();
    atomicAdd(&len_sh, cnt);

    // E column -> registers (coalesced across j for each k)
    float Ecol[NLAB];
    #pragma unroll
    for (int k = 0; k < NLAB; ++k) Ecol[k] = E[k * NLAB + j];
    __syncthreads();
    const int len = len_sh;  // >= 256 always

    float fv = tr[BOS_ * NLAB + j] + feats[(size_t)b * TT * NLAB + j];
    float feat_next = feats[((size_t)b * TT + 1) * NLAB + j];

    for (int t = 1; t < len; ++t) {
        const float feat = feat_next;
        if (t + 1 < len)
            feat_next = feats[((size_t)b * TT + t + 1) * NLAB + j];

        // block max of fv
        float m = fv;
        #pragma unroll
        for (int off = 32; off > 0; off >>= 1)
            m = fmaxf(m, __shfl_xor(m, off, 64));
        if ((j & 63) == 0) red[j >> 6] = m;
        __syncthreads();
        m = fmaxf(red[0], red[1]);

        p_sh[j] = __expf(fv - m);
        __syncthreads();

        // s_j = sum_k p[k] * E[k][j], p via float4 broadcast reads
        float4 s4 = make_float4(0.f, 0.f, 0.f, 0.f);
        const float4* p4 = (const float4*)p_sh;
        #pragma unroll
        for (int k4 = 0; k4 < NLAB / 4; ++k4) {
            const float4 pv = p4[k4];
            s4.x += pv.x * Ecol[4 * k4 + 0];
            s4.y += pv.y * Ecol[4 * k4 + 1];
            s4.z += pv.z * Ecol[4 * k4 + 2];
            s4.w += pv.w * Ecol[4 * k4 + 3];
        }
        const float s = (s4.x + s4.y) + (s4.z + s4.w);
        fv = m + __logf(s) + feat;   // -inf stays -inf for dead labels: ok
        __syncthreads();             // protect p_sh/red for next iteration
    }

    // logZ = logsumexp_j(fv + tr[j, EOS])
    const float v = fv + tr[j * NLAB + EOS_];
    float m = v;
    #pragma unroll
    for (int off = 32; off > 0; off >>= 1)
        m = fmaxf(m, __shfl_xor(m, off, 64));
    if ((j & 63) == 0) red[j >> 6] = m;
    __syncthreads();
    m = fmaxf(red[0], red[1]);
    float e = __expf(v - m);
    #pragma unroll
    for (int off = 32; off > 0; off >>= 1)
        e += __shfl_xor(e, off, 64);
    if ((j & 63) == 0) red2[j >> 6] = e;
    __syncthreads();
    if (j == 0) logZ_out[b] = m + __logf(red2[0] + red2[1]);
}

// ---- final reduction: out = mean(logZ - gold) ------------------------------
__global__ void crf_finalize(const float* __restrict__ gold,
                             const float* __restrict__ logZ,
                             float* __restrict__ out) {
    __shared__ float sh[4];
    const int i = threadIdx.x;  // 256 threads
    float v = (logZ[i] - gold[i]) + (logZ[i + 256] - gold[i + 256]);
    #pragma unroll
    for (int off = 32; off > 0; off >>= 1)
        v += __shfl_xor(v, off, 64);
    if ((i & 63) == 0) sh[i >> 6] = v;
    __syncthreads();
    if (i == 0) out[0] = (sh[0] + sh[1] + sh[2] + sh[3]) * (1.0f / (float)BB);
}

extern "C" void kernel_launch(void* const* d_in, const int* in_sizes, int n_in,
                              void* d_out, int out_size, void* d_ws, size_t ws_size,
                              hipStream_t stream) {
    const float*         feats = (const float*)d_in[0];
    const int*           tags  = (const int*)d_in[1];
    const unsigned char* m8    = (const unsigned char*)d_in[2];
    const float*         tr    = (const float*)d_in[3];

    float* E    = (float*)d_ws;              // 128*128 floats
    float* gold = E + NLAB * NLAB;           // 512 floats
    float* logZ = gold + BB;                 // 512 floats
    float* out  = (float*)d_out;

    hipLaunchKernelGGL(crf_exp_tr,   dim3((NLAB * NLAB + 255) / 256), dim3(256), 0, stream, tr, E);
    hipLaunchKernelGGL(crf_gold,     dim3(BB), dim3(64),   0, stream, feats, tags, m8, tr, gold);
    hipLaunchKernelGGL(crf_forward,  dim3(BB), dim3(NLAB), 0, stream, feats, m8, tr, E, logZ);
    hipLaunchKernelGGL(crf_finalize, dim3(1),  dim3(256),  0, stream, gold, logZ, out);
}

// Round 2
// 476.261 us; speedup vs baseline: 1.6266x; 1.6266x over previous
//
#include <hip/hip_runtime.h>
#include <cstdint>
#include <cstddef>

#define NLAB 128
#define TT   512
#define BB   512
#define PAD_ 0
#define BOS_ 1
#define EOS_ 2

typedef float v2f __attribute__((ext_vector_type(2)));

// ---- mask dtype hedge: bool(1B) vs int32(4B) -------------------------------
// mask[0][1] is always true (lengths >= 256). int32 storage => byte 1 is the
// high byte of element 0 => 0; bool storage => 1.
__device__ __forceinline__ bool mask_is_i32(const unsigned char* m8) {
    return m8[1] == 0;
}
__device__ __forceinline__ bool mask_at(const unsigned char* m8, int idx, bool isi) {
    if (isi) return ((const int*)m8)[idx] != 0;
    return m8[idx] != 0;
}

// ---- forward + gold fused: one block (128 thr) per batch -------------------
// Thread j owns fv[j] (pre-normalized as u, true fv = u + C) and E[:,j] in 128
// VGPRs (asm-forced). Per step: ONE barrier. Normalizer is label 3's u from
// two steps back, broadcast via double-buffered LDS slot (no max-reduce).
__global__ __launch_bounds__(NLAB) void crf_forward(
        const float* __restrict__ feats,
        const int*   __restrict__ tags,
        const unsigned char* __restrict__ m8,
        const float* __restrict__ tr,
        float* __restrict__ gold_out,
        float* __restrict__ logZ_out) {
    const int b = blockIdx.x;
    const int j = threadIdx.x;
    const bool isi = mask_is_i32(m8);

    __shared__ __align__(16) float p_sh[2][NLAB];
    __shared__ float u3_sh[2];
    __shared__ float red[2], red2[2];
    __shared__ float gsh[2];
    __shared__ int   csh[2];

    const size_t fbase = (size_t)b * TT * NLAB;

    // ---- fused gold score + length (each thread: 4 timesteps) ----
    float gpart = 0.f;
    int   cnt   = 0;
    #pragma unroll
    for (int tt = j; tt < TT; tt += NLAB) {
        const int idx = b * TT + tt;
        const bool mm = mask_at(m8, idx, isi);
        cnt += mm ? 1 : 0;
        const int tag = tags[idx];
        if (tt == 0) {
            gpart += feats[fbase + tag] + tr[BOS_ * NLAB + tag];
        } else if (mm) {
            gpart += feats[fbase + (size_t)tt * NLAB + tag]
                   + tr[tags[idx - 1] * NLAB + tag];
        }
    }
    #pragma unroll
    for (int off = 32; off > 0; off >>= 1) {
        gpart += __shfl_down(gpart, off, 64);
        cnt   += __shfl_down(cnt,   off, 64);
    }
    if ((j & 63) == 0) { gsh[j >> 6] = gpart; csh[j >> 6] = cnt; }

    // ---- E column -> registers, asm-forced so loads can't sink into loop ----
    v2f Ecol2[NLAB / 2];
    #pragma unroll
    for (int k2 = 0; k2 < NLAB / 2; ++k2) {
        float e0 = __expf(tr[(2 * k2 + 0) * NLAB + j]);   // exp(-10000) -> 0
        float e1 = __expf(tr[(2 * k2 + 1) * NLAB + j]);
        asm volatile("" : "+v"(e0), "+v"(e1));
        v2f e; e.x = e0; e.y = e1;
        Ecol2[k2] = e;
    }

    // ---- init ----
    float u = tr[BOS_ * NLAB + j] + feats[fbase + j];
    if (j == 3) u3_sh[0] = u;     // label 3 is always live (not PAD/BOS/EOS)
    __syncthreads();

    const int len = csh[0] + csh[1];   // >= 256 always
    if (j == 0) {
        const int last = tags[b * TT + (len - 1)];
        gold_out[b] = gsh[0] + gsh[1] + tr[last * NLAB + EOS_];
    }

    float norm = u3_sh[0];   // normalizer for step t; lagged, never -inf
    float C = 0.f;           // accumulated shifts: true fv = u + C
    float feat_next  = feats[fbase + 1 * NLAB + j];
    float feat_next2 = feats[fbase + 2 * NLAB + j];

    for (int t = 1; t < len; ++t) {
        const float p = __expf(u - norm);
        C += norm;
        p_sh[t & 1][j] = p;
        const float ft = feat_next;
        feat_next = feat_next2;
        const int tpre = (t + 2 < len) ? (t + 2) : (len - 1);
        feat_next2 = feats[fbase + (size_t)tpre * NLAB + j];
        __syncthreads();                       // the ONLY barrier per step
        const float nn = u3_sh[(t - 1) & 1];   // normalizer for step t+1 (lagged)

        // s_j = sum_k p[k] * E[k][j] : packed fp32 FMA out of VGPR-resident E
        v2f acc0 = {0.f, 0.f}, acc1 = {0.f, 0.f}, acc2 = {0.f, 0.f}, acc3 = {0.f, 0.f};
        const float4* p4 = (const float4*)p_sh[t & 1];
        #pragma unroll
        for (int k4 = 0; k4 < NLAB / 4; ++k4) {
            const float4 pv = p4[k4];
            v2f plo; plo.x = pv.x; plo.y = pv.y;
            v2f phi; phi.x = pv.z; phi.y = pv.w;
            if (k4 & 1) {
                acc2 = __builtin_elementwise_fma(plo, Ecol2[2 * k4 + 0], acc2);
                acc3 = __builtin_elementwise_fma(phi, Ecol2[2 * k4 + 1], acc3);
            } else {
                acc0 = __builtin_elementwise_fma(plo, Ecol2[2 * k4 + 0], acc0);
                acc1 = __builtin_elementwise_fma(phi, Ecol2[2 * k4 + 1], acc1);
            }
        }
        const v2f accs = (acc0 + acc1) + (acc2 + acc3);
        const float s = accs.x + accs.y;       // 0 for dead columns -> -inf: ok

        u = __logf(s) + ft;
        if (j == 3) u3_sh[t & 1] = u;          // consumed at step t+1 after its barrier
        norm = nn;
    }

    // ---- logZ = C + logsumexp_j(u + tr[j, EOS]) (exact max-based, once) ----
    const float v = u + tr[j * NLAB + EOS_];
    float m = v;
    #pragma unroll
    for (int off = 32; off > 0; off >>= 1)
        m = fmaxf(m, __shfl_xor(m, off, 64));
    if ((j & 63) == 0) red[j >> 6] = m;
    __syncthreads();
    m = fmaxf(red[0], red[1]);
    float e = __expf(v - m);
    #pragma unroll
    for (int off = 32; off > 0; off >>= 1)
        e += __shfl_xor(e, off, 64);
    if ((j & 63) == 0) red2[j >> 6] = e;
    __syncthreads();
    if (j == 0) logZ_out[b] = C + m + __logf(red2[0] + red2[1]);
}

// ---- final reduction: out = mean(logZ - gold) ------------------------------
__global__ void crf_finalize(const float* __restrict__ gold,
                             const float* __restrict__ logZ,
                             float* __restrict__ out) {
    __shared__ float sh[4];
    const int i = threadIdx.x;  // 256 threads
    float v = (logZ[i] - gold[i]) + (logZ[i + 256] - gold[i + 256]);
    #pragma unroll
    for (int off = 32; off > 0; off >>= 1)
        v += __shfl_xor(v, off, 64);
    if ((i & 63) == 0) sh[i >> 6] = v;
    __syncthreads();
    if (i == 0) out[0] = (sh[0] + sh[1] + sh[2] + sh[3]) * (1.0f / (float)BB);
}

extern "C" void kernel_launch(void* const* d_in, const int* in_sizes, int n_in,
                              void* d_out, int out_size, void* d_ws, size_t ws_size,
                              hipStream_t stream) {
    const float*         feats = (const float*)d_in[0];
    const int*           tags  = (const int*)d_in[1];
    const unsigned char* m8    = (const unsigned char*)d_in[2];
    const float*         tr    = (const float*)d_in[3];

    float* gold = (float*)d_ws;       // 512 floats
    float* logZ = gold + BB;          // 512 floats
    float* out  = (float*)d_out;

    hipLaunchKernelGGL(crf_forward,  dim3(BB), dim3(NLAB), 0, stream,
                       feats, tags, m8, tr, gold, logZ);
    hipLaunchKernelGGL(crf_finalize, dim3(1),  dim3(256),  0, stream,
                       gold, logZ, out);
}